// Round 11
// baseline (131.730 us; speedup 1.0000x reference)
//
#include <hip/hip_runtime.h>

// FocalSelfAttention on MI355X. fp32 I/O, bf16 MFMA compute, fp32 accum.
// B=4, C=128, H=W=48, WS=4 -> 144 windows/batch, 16 q/window, NH=8, hd=16,
// Nkv = 64 local + 720 pooled.
//
// v19 = v18 (best: 129.1 us, attn 52.4, spill-free barrier-free loop) with
// three attn-only changes:
//  1. KP XOR-swizzle: elem (r,c) at byte (r*32+c*2)^((r&7)<<4). v18's
//     [64][16] rows gave 4-way read conflicts (3.05M SQ_LDS_BANK_CONFLICT);
//     swizzled reads are exactly 2-way (free per m136), writes cover all
//     32 banks (was 16).
//  2. V-fragment prefetch 1 tile ahead (flat vpC/vpN rotation, static
//     offsets -- the spill-safe form). Hides V L2 latency under compute.
//  3. __launch_bounds__(512,3): cap ~85 VGPR (demand ~72 incl. prefetch),
//     and 576 blocks all co-resident at <=3 blocks/CU (no tail).
// prep / gemm_kv identical to v18.

typedef unsigned short u16;
typedef short v8s __attribute__((ext_vector_type(8)));
typedef v8s __attribute__((may_alias)) v8s_am;
typedef short v4s __attribute__((ext_vector_type(4)));
typedef v4s __attribute__((may_alias)) v4s_am;
typedef float v4f __attribute__((ext_vector_type(4)));

#define MFMA_BF16(a, b, c) __builtin_amdgcn_mfma_f32_16x16x32_bf16(a, b, c, 0, 0, 0)

#if __has_builtin(__builtin_amdgcn_mfma_f32_16x16x16bf16_1k)
#define MFMA16(a, b, c) __builtin_amdgcn_mfma_f32_16x16x16bf16_1k(a, b, c, 0, 0, 0)
#else
static __device__ __forceinline__ v4f mfma16_fb(v4s a, v4s b, v4f c) {
    v8s a8 = {a[0], a[1], a[2], a[3], 0, 0, 0, 0};
    v8s b8 = {b[0], b[1], b[2], b[3], 0, 0, 0, 0};
    return MFMA_BF16(a8, b8, c);
}
#define MFMA16(a, b, c) mfma16_fb(a, b, c)
#endif

#if __has_builtin(__builtin_amdgcn_exp2f)
#define EXP2(x) __builtin_amdgcn_exp2f(x)
#else
#define EXP2(x) exp2f(x)
#endif

__device__ __forceinline__ float b2f(u16 u) {
    union { unsigned int i; float f; } x;
    x.i = ((unsigned int)u) << 16;
    return x.f;
}
__device__ __forceinline__ u16 f2b(float f) {
    union { float f; unsigned int i; } x;
    x.f = f;
    unsigned int u = x.i;
    return (u16)((u + 0x7fffu + ((u >> 16) & 1u)) >> 16);
}

// ---------------------------------------------------------------------------
// Kernel 1: blocks 0..287 transpose F->Xt + LN stats; 288..303 weights;
// 304..483 pooled tokens -> Pml. (v12 structure, best measured.)
__global__ __launch_bounds__(256) void k_prep(
    const float* __restrict__ F,
    const float* __restrict__ qw, const float* __restrict__ kvw,
    const float* __restrict__ ow,
    const float* __restrict__ lnw, const float* __restrict__ lnb,
    u16* __restrict__ Xt, u16* __restrict__ Wb, float* __restrict__ MuRs,
    u16* __restrict__ Pml)
{
    int blk = blockIdx.x;
    int t = threadIdx.x;
    if (blk >= 304) {   // ---- pool part: 180 blocks ----
        int gid = (blk - 304) * 256 + t;
        int row = gid >> 4;
        int seg = gid & 15;
        v8s outv;
        if (row < 2304) {        // mid: avg 2x2
            int b = row / 576, r = row % 576;
            int i = r / 24, j = r % 24;
#pragma unroll
            for (int jc = 0; jc < 8; ++jc) {
                int c = seg * 8 + jc;
                const float* src = F + ((size_t)(b * 128 + c)) * 2304 + (2 * i) * 48 + 2 * j;
                float2 a = *(const float2*)src;
                float2 d = *(const float2*)(src + 48);
                outv[jc] = (short)f2b((a.x + a.y + d.x + d.y) * 0.25f);
            }
        } else {                 // glo: avg 4x4
            int r2 = row - 2304;
            int b = r2 / 144, r = r2 % 144;
            int i = r / 12, j = r % 12;
#pragma unroll
            for (int jc = 0; jc < 8; ++jc) {
                int c = seg * 8 + jc;
                const float* src = F + ((size_t)(b * 128 + c)) * 2304 + (4 * i) * 48 + 4 * j;
                float s = 0.f;
#pragma unroll
                for (int di = 0; di < 4; ++di) {
                    float4 v = *(const float4*)(src + di * 48);
                    s += (v.x + v.y) + (v.z + v.w);
                }
                outv[jc] = (short)f2b(s * 0.0625f);
            }
        }
        *(v8s_am*)&Pml[((size_t)row) * 128 + seg * 8] = outv;
        return;
    }
    if (blk >= 288) {   // ---- weight conversion: 16 blocks ----
        int base = (blk - 288) * 4096 + t * 16;
#pragma unroll
        for (int i = 0; i < 4; ++i) {
            int idx = base + i * 4;
            const float* src; int off;
            if (idx < 16384)      { src = qw;  off = idx; }
            else if (idx < 49152) { src = kvw; off = idx - 16384; }
            else                  { src = ow;  off = idx - 49152; }
            float4 v = *(const float4*)(src + off);
            unsigned long long packed =
                (unsigned long long)f2b(v.x) |
                ((unsigned long long)f2b(v.y) << 16) |
                ((unsigned long long)f2b(v.z) << 32) |
                ((unsigned long long)f2b(v.w) << 48);
            *(unsigned long long*)(Wb + idx) = packed;
        }
        if (blk == 288) {
            Wb[65536 + t] = f2b(t < 128 ? lnw[t] : lnb[t - 128]);
        }
        return;
    }
    // ---- transpose + LN stats: 288 blocks ----
    __shared__ u16 X[128][34];
    int b = blk / 72;
    int p0 = (blk % 72) * 32;
#pragma unroll 4
    for (int i = 0; i < 16; ++i) {
        int c = i * 8 + (t >> 5);
        int pix = t & 31;
        X[c][pix] = f2b(F[((size_t)(b * 128 + c)) * 2304 + p0 + pix]);
    }
    __syncthreads();
    int pix = t >> 3;
    int c0 = (t & 7) * 16;
    size_t row = (size_t)(b * 2304 + p0 + pix) * 128;
    float s = 0.f, s2 = 0.f;
#pragma unroll
    for (int sg = 0; sg < 2; ++sg) {
        v8s raw;
#pragma unroll
        for (int j = 0; j < 8; ++j) {
            u16 u = X[c0 + sg * 8 + j][pix];
            raw[j] = (short)u;
            float v = b2f(u);
            s += v; s2 += v * v;
        }
        *(v8s_am*)&Xt[row + c0 + sg * 8] = raw;
    }
    s += __shfl_xor(s, 1);  s2 += __shfl_xor(s2, 1);
    s += __shfl_xor(s, 2);  s2 += __shfl_xor(s2, 2);
    s += __shfl_xor(s, 4);  s2 += __shfl_xor(s2, 4);
    if ((t & 7) == 0) {
        float mean = s * (1.f / 128.f);
        float var = s2 * (1.f / 128.f) - mean * mean;
        float rstd = rsqrtf(var + 1e-5f);
        MuRs[(b * 2304 + p0 + pix) * 2]     = mean;
        MuRs[(b * 2304 + p0 + pix) * 2 + 1] = rstd;
    }
}

// ---------------------------------------------------------------------------
// Kernel 2: mid/glo K/V projection from Pml (v12 structure).
// K -> HEAD-MAJOR KVh[8][2880][16]; V -> VTg[b][128 ch][720 tok].
__global__ __launch_bounds__(256) void k_gemm_kv(
    const u16* __restrict__ Pml,
    const u16* __restrict__ W,
    const float* __restrict__ bias,
    u16* __restrict__ KVh,
    u16* __restrict__ VTg)
{
    __shared__ u16 Al[64][136];
    __shared__ u16 Wl[64][136];
    int tm = blockIdx.x * 64, tn = blockIdx.y * 64;
    int t = threadIdx.x;
    {
        int seg = t & 15, r0 = t >> 4;
#pragma unroll
        for (int i = 0; i < 4; ++i) {
            int r = r0 + 16 * i;
            *(v8s_am*)&Al[r][seg * 8] = *(const v8s_am*)&Pml[((size_t)(tm + r)) * 128 + seg * 8];
            *(v8s_am*)&Wl[r][seg * 8] = *(const v8s_am*)&W[((size_t)(tn + r)) * 128 + seg * 8];
        }
    }
    __syncthreads();
    int lane = t & 63, wave = t >> 6;
    int n15 = lane & 15, quad = lane >> 4;
    int wm = (wave & 1) * 32, wn = (wave >> 1) * 32;
    v4f acc[2][2] = {};
#pragma unroll
    for (int kc = 0; kc < 4; ++kc) {
        v8s a[2], bb[2];
#pragma unroll
        for (int im = 0; im < 2; ++im)
            a[im] = *(const v8s_am*)&Al[wm + im * 16 + n15][kc * 32 + quad * 8];
#pragma unroll
        for (int in = 0; in < 2; ++in)
            bb[in] = *(const v8s_am*)&Wl[wn + in * 16 + n15][kc * 32 + quad * 8];
#pragma unroll
        for (int im = 0; im < 2; ++im)
#pragma unroll
            for (int in = 0; in < 2; ++in)
                acc[im][in] = MFMA_BF16(a[im], bb[in], acc[im][in]);
    }
#pragma unroll
    for (int in = 0; in < 2; ++in) {
        int n = tn + wn + in * 16 + n15;
        float bv = bias[n];
#pragma unroll
        for (int im = 0; im < 2; ++im) {
            int mbase = tm + wm + im * 16 + quad * 4;
#pragma unroll
            for (int r = 0; r < 4; ++r) {
                int m = mbase + r;
                u16 h = f2b(acc[im][in][r] + bv);
                if (n < 128) {
                    KVh[((size_t)(n >> 4) * 2880 + m) * 16 + (n & 15)] = h;
                } else {
                    int ch = n - 128, bb2, tok;
                    if (m < 2304) { bb2 = m / 576; tok = m % 576; }
                    else { int r2 = m - 2304; bb2 = r2 / 144; tok = 576 + r2 % 144; }
                    VTg[((size_t)(bb2 * 128 + ch)) * 720 + tok] = h;
                }
            }
        }
    }
}

// ---------------------------------------------------------------------------
// Kernel 3: fused attention. 576 blocks x 512 thr (8 waves), wave = head,
// 1 window/block. Barrier-free pooled loop via wave-private single-buffer
// KP (per-wave in-order DS), XOR-swizzled banks, V prefetch 1 tile ahead.
// (512,3): cap ~85 VGPR, <=3 blocks/CU -> all 576 blocks co-resident.
__global__ __launch_bounds__(512, 3) void k_attn_fused(
    const float* __restrict__ F,
    const u16* __restrict__ Xt,
    const float* __restrict__ MuRs,
    const u16* __restrict__ KVh,     // [8][2880][16] head-major
    const u16* __restrict__ VTg,
    const u16* __restrict__ Wb,      // [qwb|kvwb|owb|lnwb|lnbb]
    const float* __restrict__ qb,
    const float* __restrict__ kvb,
    const float* __restrict__ ob,
    float* __restrict__ Out)
{
    __shared__ u16 KP[8][64][16];    // wave-private K tile, XOR-swizzled (16 KB)
    __shared__ u16 VtW[8][16][68];   // per-wave local V^T (17.4 KB)

    const u16* qwb  = Wb;
    const u16* kvwb = Wb + 16384;
    const u16* owb  = Wb + 49152;
    const u16* lnwb = Wb + 65536;
    const u16* lnbb = Wb + 65664;
    u16* Atp = &VtW[0][0][0];        // overlay [16][136] = 2176 u16

    // Bijective XCD swizzle: xcd = blk&7 -> one batch-half per XCD.
    int blk = blockIdx.x;
    int xcd = blk & 7, jj = blk >> 3;   // jj 0..71
    int b = xcd >> 1;
    int wr = (xcd & 1) * 6 + jj / 12;
    int wc = jj % 12;

    int t = threadIdx.x;
    int lane = t & 63, wave = t >> 6, n15 = lane & 15, quad = lane >> 4;
    v8s zf8 = {};
    v4f zz4 = {0.f, 0.f, 0.f, 0.f};
    const float QSCALE = 0.25f * 1.44269504f;

    // KP swizzle: elem (row r, col c) at byte (r*32 + c*2) ^ ((r&7)<<4).
    // Reads (per g): 2-way bank conflict max (free); writes hit all 32 banks.
    char* KPb = (char*)&KP[wave][0][0];
    int swW = (lane & 7) << 4;
    int wb0 = (lane * 32) ^ swW;            // write half 0 (16B aligned)
    int wb1 = (lane * 32 + 16) ^ swW;       // write half 1
    int rdb = (n15 * 32 + quad * 8) ^ ((n15 & 7) << 4);  // + g*512 per g

    const u16* kwave = KVh + (size_t)wave * 46080;   // this head's K rows
    const u16* vrow0 = VTg + (size_t)b * 92160
                     + (size_t)(wave * 16 + n15) * 720 + quad * 4;

    // --- issue tile-0 K slice (contiguous 2KB/wave) immediately ---
    v8s kN0, kN1;
    {
        const u16* s = kwave + (size_t)(b * 576 + lane) * 16;
        kN0 = *(const v8s_am*)s; kN1 = *(const v8s_am*)(s + 8);
    }

    // --- per-lane LN'd window token B-fragments (tok = n15) ---
    int qh = wr * 4 + (n15 >> 2), qw_ = wc * 4 + (n15 & 3);
    int qpix = b * 2304 + qh * 48 + qw_;
    float mu = MuRs[qpix * 2], rstd = MuRs[qpix * 2 + 1];
    v8s xln[4];
#pragma unroll
    for (int kc = 0; kc < 4; ++kc) {
        v8s x  = *(const v8s_am*)&Xt[(size_t)qpix * 128 + kc * 32 + quad * 8];
        v8s lw = *(const v8s_am*)&lnwb[kc * 32 + quad * 8];
        v8s lb = *(const v8s_am*)&lnbb[kc * 32 + quad * 8];
        v8s y;
#pragma unroll
        for (int j = 0; j < 8; ++j)
            y[j] = (short)f2b((b2f((u16)x[j]) - mu) * rstd * b2f((u16)lw[j]) + b2f((u16)lb[j]));
        xln[kc] = y;
    }

    // --- Q projection TRANSPOSED for head=wave: D[d=quad*4+r][q=n15] ---
    v4s qf;
    {
        int n0 = wave * 16;
        v4f qacc = zz4;
#pragma unroll
        for (int kc = 0; kc < 4; ++kc) {
            v8s aw = *(const v8s_am*)&qwb[((size_t)(n0 + n15)) * 128 + kc * 32 + quad * 8];
            qacc = MFMA_BF16(aw, xln[kc], qacc);
        }
#pragma unroll
        for (int r = 0; r < 4; ++r)
            qf[r] = (short)f2b((qacc[r] + qb[n0 + quad * 4 + r]) * QSCALE);
    }

    // --- local K/V projection TRANSPOSED (this wave's head only) ---
    v4s kfloc[4];
#pragma unroll
    for (int g = 0; g < 4; ++g) {
        int tl = g * 16 + n15;
        int fh = tl >> 3, fw = tl & 7;
        int hh = wr * 4 - 2 + fh, ww = wc * 4 - 2 + fw;
        bool valid = (hh >= 0 && hh < 48 && ww >= 0 && ww < 48);
        size_t arow = (size_t)(b * 2304 + hh * 48 + ww) * 128;
        v8s xb[4];
#pragma unroll
        for (int kc = 0; kc < 4; ++kc) {
            v8s v = zf8;
            if (valid) v = *(const v8s_am*)&Xt[arow + kc * 32 + quad * 8];
            xb[kc] = v;
        }
#pragma unroll
        for (int s = 0; s < 2; ++s) {    // s=0: K strip, s=1: V strip
            int sbase = s * 128 + wave * 16;
            v4f acc = zz4;
#pragma unroll
            for (int kc = 0; kc < 4; ++kc) {
                v8s aw = *(const v8s_am*)&kvwb[((size_t)(sbase + n15)) * 128 + kc * 32 + quad * 8];
                acc = MFMA_BF16(aw, xb[kc], acc);
            }
            if (s == 0) {
                v4s k4;
#pragma unroll
                for (int r = 0; r < 4; ++r)
                    k4[r] = (short)f2b(acc[r] + kvb[sbase + quad * 4 + r]);
                kfloc[g] = k4;
            } else {
#pragma unroll
                for (int r = 0; r < 4; ++r)
                    VtW[wave][quad * 4 + r][g * 16 + n15] =
                        f2b(acc[r] + kvb[sbase + quad * 4 + r]);
            }
        }
    }

    v4f oacc = zz4;
    float ls = 0.f;

    // --- local chunk (K frags in regs, V from wave-private LDS slice) ---
    asm volatile("s_waitcnt lgkmcnt(0)" ::: "memory");
#pragma unroll
    for (int g = 0; g < 4; ++g) {
        v4f St = MFMA16(kfloc[g], qf, zz4);     // S^T[tok=quad*4+r][q=n15]
        float p0 = EXP2(St[0]), p1 = EXP2(St[1]);
        float p2 = EXP2(St[2]), p3 = EXP2(St[3]);
        ls += (p0 + p1) + (p2 + p3);
        v4s pk = {(short)f2b(p0), (short)f2b(p1), (short)f2b(p2), (short)f2b(p3)};
        v4s vf = *(const v4s_am*)&VtW[wave][n15][g * 16 + quad * 4];
        oacc = MFMA16(vf, pk, oacc);            // O^T[ch=quad*4+r][q=n15]
    }
    // All VtW reads done -> later At-overlay writes can't race them.
    __syncthreads();    // barrier 1

    // --- stage tile 0 (swizzled); issue tile-1 K; prefetch V(tile 0) ---
    *(v8s_am*)(KPb + wb0) = kN0;
    *(v8s_am*)(KPb + wb1) = kN1;
    {
        const u16* s = kwave + (size_t)(b * 576 + 64 + lane) * 16;
        kN0 = *(const v8s_am*)s; kN1 = *(const v8s_am*)(s + 8);
    }
    v4s vpC[4], vpN[4];
#pragma unroll
    for (int g = 0; g < 4; ++g) vpC[g] = *(const v4s_am*)(vrow0 + g * 16);

    // --- pooled tiles 0..10: barrier-free, wave-private single buffer ---
    for (int tb = 0; tb <= 10; ++tb) {
        // read tile tb's K fragments (DS in-order: reads precede the write)
        v4s kf[4];
#pragma unroll
        for (int g = 0; g < 4; ++g)
            kf[g] = *(const v4s_am*)(KPb + rdb + g * 512);
        // overwrite KP with tile tb+1
        *(v8s_am*)(KPb + wb0) = kN0;
        *(v8s_am*)(KPb + wb1) = kN1;
        if (tb < 10) {   // issue K(tb+2): tiles 2..11
            int t2 = tb + 2;
            int row = (t2 < 9) ? (b * 576 + t2 * 64 + lane)
                               : (2304 + b * 144 + (t2 - 9) * 64 + lane);
            if (t2 == 11) row = 2304 + b * 144 + 128 + n15;  // 16 rows, dup x4
            const u16* s = kwave + (size_t)row * 16;
            kN0 = *(const v8s_am*)s; kN1 = *(const v8s_am*)(s + 8);
        }
        // prefetch V(tb+1); at tb==10 that's tile 11 (16 toks, off 704)
        {
            int o1 = (tb == 10) ? 704 : (tb + 1) * 64;
#pragma unroll
            for (int g = 0; g < 4; ++g) {
                int off = (tb == 10) ? 704 : (o1 + g * 16);
                vpN[g] = *(const v4s_am*)(vrow0 + off);
            }
        }
        // compute tile tb with vpC
#pragma unroll
        for (int g = 0; g < 4; ++g) {
            v4f St = MFMA16(kf[g], qf, zz4);
            float p0 = EXP2(St[0]), p1 = EXP2(St[1]);
            float p2 = EXP2(St[2]), p3 = EXP2(St[3]);
            ls += (p0 + p1) + (p2 + p3);
            v4s pk = {(short)f2b(p0), (short)f2b(p1), (short)f2b(p2), (short)f2b(p3)};
            oacc = MFMA16(vpC[g], pk, oacc);
        }
#pragma unroll
        for (int g = 0; g < 4; ++g) vpC[g] = vpN[g];
    }
    // --- tile 11: 16 toks (glo 128..143), staged at tb==10; V in vpC[0] ---
    {
        v4s kf = *(const v4s_am*)(KPb + rdb);
        v4f St = MFMA16(kf, qf, zz4);
        float p0 = EXP2(St[0]), p1 = EXP2(St[1]);
        float p2 = EXP2(St[2]), p3 = EXP2(St[3]);
        ls += (p0 + p1) + (p2 + p3);
        v4s pk = {(short)f2b(p0), (short)f2b(p1), (short)f2b(p2), (short)f2b(p3)};
        oacc = MFMA16(vpC[0], pk, oacc);
    }

    // --- l reduce (across quads); write attended into At overlay ---
    ls += __shfl_xor(ls, 16);
    ls += __shfl_xor(ls, 32);
    {
        float inv = 1.f / ls;
        v4s a4 = {(short)f2b(oacc[0] * inv), (short)f2b(oacc[1] * inv),
                  (short)f2b(oacc[2] * inv), (short)f2b(oacc[3] * inv)};
        *(v4s_am*)&Atp[n15 * 136 + wave * 16 + quad * 4] = a4;
    }
    __syncthreads();    // barrier 2: At complete before out-proj reads

    // --- out projection (16 out-ch per wave) + bias + residual, NCHW ---
    {
        int n0 = wave * 16;
        v4f oa = zz4;
#pragma unroll
        for (int kc = 0; kc < 4; ++kc) {
            v8s af = *(const v8s_am*)&Atp[n15 * 136 + kc * 32 + quad * 8];
            v8s bf = *(const v8s_am*)&owb[((size_t)(n0 + n15)) * 128 + kc * 32 + quad * 8];
            oa = MFMA_BF16(af, bf, oa);
        }
        int c = n0 + n15;
        float bv = ob[c];
#pragma unroll
        for (int r = 0; r < 4; ++r) {
            int pix = quad * 4 + r;
            int hh = wr * 4 + (pix >> 2), ww_ = wc * 4 + (pix & 3);
            size_t idx = ((size_t)(b * 128 + c)) * 2304 + hh * 48 + ww_;
            Out[idx] = oa[r] + bv + F[idx];
        }
    }
}

// ---------------------------------------------------------------------------
extern "C" void kernel_launch(void* const* d_in, const int* in_sizes, int n_in,
                              void* d_out, int out_size, void* d_ws, size_t ws_size,
                              hipStream_t stream)
{
    const float* F   = (const float*)d_in[0];
    const float* lnw = (const float*)d_in[1];
    const float* lnb = (const float*)d_in[2];
    const float* qw  = (const float*)d_in[3];
    const float* qb  = (const float*)d_in[4];
    const float* kvw = (const float*)d_in[5];
    const float* kvb = (const float*)d_in[6];
    const float* ow  = (const float*)d_in[7];
    const float* ob  = (const float*)d_in[8];
    float* Out = (float*)d_out;

    u16* ws    = (u16*)d_ws;
    u16* Xt    = ws;                    // 9216*128  = 1,179,648 u16
    u16* Pml   = Xt + 9216 * 128;       // 2880*128  =   368,640
    u16* KVh   = Pml + 2880 * 128;      // 8*2880*16 =   368,640 (head-major)
    u16* VTg   = KVh + 8 * 2880 * 16;   // 4*128*720 =   368,640
    u16* Wb    = VTg + 4 * 128 * 720;   // 65,792 [qwb|kvwb|owb|lnwb|lnbb]
    float* MuRs = (float*)(Wb + 65792); // 9216*2 fp32
    // total: ~4.77 MiB
    u16* kvwb = Wb + 16384;

    k_prep<<<484, 256, 0, stream>>>(F, qw, kvw, ow, lnw, lnb, Xt, Wb, MuRs, Pml);
    k_gemm_kv<<<dim3(45, 4), 256, 0, stream>>>(Pml, kvwb, kvb, KVh, VTg);
    k_attn_fused<<<576, 512, 0, stream>>>(F, Xt, MuRs, KVh, VTg, Wb,
                                          qb, kvb, ob, Out);
}

// Round 12
// 121.648 us; speedup vs baseline: 1.0829x; 1.0829x over previous
//
#include <hip/hip_runtime.h>

// FocalSelfAttention on MI355X. fp32 I/O, bf16 MFMA compute, fp32 accum.
// B=4, C=128, H=W=48, WS=4 -> 144 windows/batch, 16 q/window, NH=8, hd=16,
// Nkv = 64 local + 720 pooled.
//
// v20: move the LOCAL K/V projection out of attn into k_gemm_kv.
// Evidence: attn invariant to barriers/occupancy/conflicts (v10..v19) ->
// bound by aggregate per-CU issue + request count. Each attn wave was
// re-projecting its 64 local tokens (32 MFMA + 48 gathers + ~400 VALU),
// 4x-redundant across overlapping windows and 8x across heads reading the
// same weights. Now k_gemm_kv projects all 9216 pixel tokens once:
//   K -> Klh[8][4][2304][16] head-major (attn lane-gathers its slice,
//        invalid boundary lanes select bf16 K-bias),
//   V -> Vlh[128 ch][4 b][2704] over a zero-PADDED 52x52 image, pad
//        prefilled with V-bias (reference pads features with 0 => pad
//        token K/V = bias). V fragments become contiguous v4s reads.
// Attn loses kvw reads, 32 MFMAs, VtW buffer; ONE barrier total; LDS 20.7KB.

typedef unsigned short u16;
typedef short v8s __attribute__((ext_vector_type(8)));
typedef v8s __attribute__((may_alias)) v8s_am;
typedef short v4s __attribute__((ext_vector_type(4)));
typedef v4s __attribute__((may_alias)) v4s_am;
typedef float v4f __attribute__((ext_vector_type(4)));

#define MFMA_BF16(a, b, c) __builtin_amdgcn_mfma_f32_16x16x32_bf16(a, b, c, 0, 0, 0)

#if __has_builtin(__builtin_amdgcn_mfma_f32_16x16x16bf16_1k)
#define MFMA16(a, b, c) __builtin_amdgcn_mfma_f32_16x16x16bf16_1k(a, b, c, 0, 0, 0)
#else
static __device__ __forceinline__ v4f mfma16_fb(v4s a, v4s b, v4f c) {
    v8s a8 = {a[0], a[1], a[2], a[3], 0, 0, 0, 0};
    v8s b8 = {b[0], b[1], b[2], b[3], 0, 0, 0, 0};
    return MFMA_BF16(a8, b8, c);
}
#define MFMA16(a, b, c) mfma16_fb(a, b, c)
#endif

#if __has_builtin(__builtin_amdgcn_exp2f)
#define EXP2(x) __builtin_amdgcn_exp2f(x)
#else
#define EXP2(x) exp2f(x)
#endif

__device__ __forceinline__ float b2f(u16 u) {
    union { unsigned int i; float f; } x;
    x.i = ((unsigned int)u) << 16;
    return x.f;
}
__device__ __forceinline__ u16 f2b(float f) {
    union { float f; unsigned int i; } x;
    x.f = f;
    unsigned int u = x.i;
    return (u16)((u + 0x7fffu + ((u >> 16) & 1u)) >> 16);
}

// ---------------------------------------------------------------------------
// Kernel 1: blocks 0..287 transpose F->Xt + LN stats; 288..303 weights
// (blk 288 also ln params + bf16 kv-bias); 304..483 pooled tokens -> Pml;
// 484..652 fill Vlh with V-bias (pad stays bias after gemm overwrites
// interior -- reference zero-pads features, so pad-token V = bias).
__global__ __launch_bounds__(256) void k_prep(
    const float* __restrict__ F,
    const float* __restrict__ qw, const float* __restrict__ kvw,
    const float* __restrict__ ow,
    const float* __restrict__ lnw, const float* __restrict__ lnb,
    const float* __restrict__ kvb,
    u16* __restrict__ Xt, u16* __restrict__ Wb, float* __restrict__ MuRs,
    u16* __restrict__ Pml, u16* __restrict__ Vlh)
{
    int blk = blockIdx.x;
    int t = threadIdx.x;
    if (blk >= 484) {   // ---- Vlh bias-fill: 169 blocks x 8192 u16 ----
        int base = (blk - 484) * 8192 + t * 32;
#pragma unroll
        for (int k = 0; k < 4; ++k) {
            int off = base + k * 8;
            int ch = off / 10816;            // 4*2704 u16 per channel
            u16 bv = f2b(kvb[128 + ch]);
            v8s o = {(short)bv, (short)bv, (short)bv, (short)bv,
                     (short)bv, (short)bv, (short)bv, (short)bv};
            *(v8s_am*)&Vlh[off] = o;
        }
        return;
    }
    if (blk >= 304) {   // ---- pool part: 180 blocks ----
        int gid = (blk - 304) * 256 + t;
        int row = gid >> 4;
        int seg = gid & 15;
        v8s outv;
        if (row < 2304) {        // mid: avg 2x2
            int b = row / 576, r = row % 576;
            int i = r / 24, j = r % 24;
#pragma unroll
            for (int jc = 0; jc < 8; ++jc) {
                int c = seg * 8 + jc;
                const float* src = F + ((size_t)(b * 128 + c)) * 2304 + (2 * i) * 48 + 2 * j;
                float2 a = *(const float2*)src;
                float2 d = *(const float2*)(src + 48);
                outv[jc] = (short)f2b((a.x + a.y + d.x + d.y) * 0.25f);
            }
        } else {                 // glo: avg 4x4
            int r2 = row - 2304;
            int b = r2 / 144, r = r2 % 144;
            int i = r / 12, j = r % 12;
#pragma unroll
            for (int jc = 0; jc < 8; ++jc) {
                int c = seg * 8 + jc;
                const float* src = F + ((size_t)(b * 128 + c)) * 2304 + (4 * i) * 48 + 4 * j;
                float s = 0.f;
#pragma unroll
                for (int di = 0; di < 4; ++di) {
                    float4 v = *(const float4*)(src + di * 48);
                    s += (v.x + v.y) + (v.z + v.w);
                }
                outv[jc] = (short)f2b(s * 0.0625f);
            }
        }
        *(v8s_am*)&Pml[((size_t)row) * 128 + seg * 8] = outv;
        return;
    }
    if (blk >= 288) {   // ---- weight conversion: 16 blocks ----
        int base = (blk - 288) * 4096 + t * 16;
#pragma unroll
        for (int i = 0; i < 4; ++i) {
            int idx = base + i * 4;
            const float* src; int off;
            if (idx < 16384)      { src = qw;  off = idx; }
            else if (idx < 49152) { src = kvw; off = idx - 16384; }
            else                  { src = ow;  off = idx - 49152; }
            float4 v = *(const float4*)(src + off);
            unsigned long long packed =
                (unsigned long long)f2b(v.x) |
                ((unsigned long long)f2b(v.y) << 16) |
                ((unsigned long long)f2b(v.z) << 32) |
                ((unsigned long long)f2b(v.w) << 48);
            *(unsigned long long*)(Wb + idx) = packed;
        }
        if (blk == 288) {
            Wb[65536 + t] = f2b(t < 128 ? lnw[t] : lnb[t - 128]);
            Wb[65792 + t] = f2b(kvb[t]);     // bf16 kv-bias (K part used)
        }
        return;
    }
    // ---- transpose + LN stats: 288 blocks ----
    __shared__ u16 X[128][34];
    int b = blk / 72;
    int p0 = (blk % 72) * 32;
#pragma unroll 4
    for (int i = 0; i < 16; ++i) {
        int c = i * 8 + (t >> 5);
        int pix = t & 31;
        X[c][pix] = f2b(F[((size_t)(b * 128 + c)) * 2304 + p0 + pix]);
    }
    __syncthreads();
    int pix = t >> 3;
    int c0 = (t & 7) * 16;
    size_t row = (size_t)(b * 2304 + p0 + pix) * 128;
    float s = 0.f, s2 = 0.f;
#pragma unroll
    for (int sg = 0; sg < 2; ++sg) {
        v8s raw;
#pragma unroll
        for (int j = 0; j < 8; ++j) {
            u16 u = X[c0 + sg * 8 + j][pix];
            raw[j] = (short)u;
            float v = b2f(u);
            s += v; s2 += v * v;
        }
        *(v8s_am*)&Xt[row + c0 + sg * 8] = raw;
    }
    s += __shfl_xor(s, 1);  s2 += __shfl_xor(s2, 1);
    s += __shfl_xor(s, 2);  s2 += __shfl_xor(s2, 2);
    s += __shfl_xor(s, 4);  s2 += __shfl_xor(s2, 4);
    if ((t & 7) == 0) {
        float mean = s * (1.f / 128.f);
        float var = s2 * (1.f / 128.f) - mean * mean;
        float rstd = rsqrtf(var + 1e-5f);
        MuRs[(b * 2304 + p0 + pix) * 2]     = mean;
        MuRs[(b * 2304 + p0 + pix) * 2 + 1] = rstd;
    }
}

// ---------------------------------------------------------------------------
// Kernel 2: K/V projection for ALL tokens. Grid (189, 4):
//  gb < 144: local pixel tokens from Xt -> Klh (head-major) / Vlh (padded img)
//  gb >= 144: pooled tokens from Pml -> KVh (head-major) / VTg (transposed)
__global__ __launch_bounds__(256) void k_gemm_kv(
    const u16* __restrict__ Xt,
    const u16* __restrict__ Pml,
    const u16* __restrict__ W,
    const float* __restrict__ bias,
    u16* __restrict__ KVh,
    u16* __restrict__ VTg,
    u16* __restrict__ Klh,
    u16* __restrict__ Vlh)
{
    __shared__ u16 Al[64][136];
    __shared__ u16 Wl[64][136];
    int gb = blockIdx.x;
    bool loc = (gb < 144);
    int tm = loc ? gb * 64 : (gb - 144) * 64;
    int tn = blockIdx.y * 64;
    int t = threadIdx.x;
    {
        int seg = t & 15, r0 = t >> 4;
        const u16* A = loc ? Xt : Pml;
#pragma unroll
        for (int i = 0; i < 4; ++i) {
            int r = r0 + 16 * i;
            *(v8s_am*)&Al[r][seg * 8] = *(const v8s_am*)&A[((size_t)(tm + r)) * 128 + seg * 8];
            *(v8s_am*)&Wl[r][seg * 8] = *(const v8s_am*)&W[((size_t)(tn + r)) * 128 + seg * 8];
        }
    }
    __syncthreads();
    int lane = t & 63, wave = t >> 6;
    int n15 = lane & 15, quad = lane >> 4;
    int wm = (wave & 1) * 32, wn = (wave >> 1) * 32;
    v4f acc[2][2] = {};
#pragma unroll
    for (int kc = 0; kc < 4; ++kc) {
        v8s a[2], bb[2];
#pragma unroll
        for (int im = 0; im < 2; ++im)
            a[im] = *(const v8s_am*)&Al[wm + im * 16 + n15][kc * 32 + quad * 8];
#pragma unroll
        for (int in = 0; in < 2; ++in)
            bb[in] = *(const v8s_am*)&Wl[wn + in * 16 + n15][kc * 32 + quad * 8];
#pragma unroll
        for (int im = 0; im < 2; ++im)
#pragma unroll
            for (int in = 0; in < 2; ++in)
                acc[im][in] = MFMA_BF16(a[im], bb[in], acc[im][in]);
    }
#pragma unroll
    for (int in = 0; in < 2; ++in) {
        int n = tn + wn + in * 16 + n15;
        float bv = bias[n];
#pragma unroll
        for (int im = 0; im < 2; ++im) {
            int mbase = tm + wm + im * 16 + quad * 4;
#pragma unroll
            for (int r = 0; r < 4; ++r) {
                int m = mbase + r;
                u16 h = f2b(acc[im][in][r] + bv);
                if (loc) {
                    int b = m / 2304, px = m % 2304;
                    if (n < 128) {
                        Klh[(((size_t)(n >> 4) * 4 + b) * 2304 + px) * 16 + (n & 15)] = h;
                    } else {
                        int ch = n - 128;
                        int hh = px / 48, ww = px % 48;
                        Vlh[((size_t)(ch * 4 + b)) * 2704 + (hh + 2) * 52 + ww + 2] = h;
                    }
                } else {
                    if (n < 128) {
                        KVh[((size_t)(n >> 4) * 2880 + m) * 16 + (n & 15)] = h;
                    } else {
                        int ch = n - 128, bb2, tok;
                        if (m < 2304) { bb2 = m / 576; tok = m % 576; }
                        else { int r2 = m - 2304; bb2 = r2 / 144; tok = 576 + r2 % 144; }
                        VTg[((size_t)(bb2 * 128 + ch)) * 720 + tok] = h;
                    }
                }
            }
        }
    }
}

// ---------------------------------------------------------------------------
// Kernel 3: fused attention. 576 blocks x 512 thr (8 waves), wave = head.
// Local K/V precomputed -> attn is LN + Qproj + 13 staged tiles. Barrier-free
// loop (wave-private single-buffer KP, per-wave in-order DS). 1 barrier.
__global__ __launch_bounds__(512, 3) void k_attn_fused(
    const float* __restrict__ F,
    const u16* __restrict__ Xt,
    const float* __restrict__ MuRs,
    const u16* __restrict__ KVh,     // [8][2880][16] pooled K head-major
    const u16* __restrict__ VTg,     // [4][128][720] pooled V^T
    const u16* __restrict__ Klh,     // [8][4][2304][16] local K head-major
    const u16* __restrict__ Vlh,     // [128][4][2704] local V^T padded 52x52
    const u16* __restrict__ Wb,      // [qwb|kvwb|owb|lnwb|lnbb|kvbb]
    const float* __restrict__ qb,
    const float* __restrict__ ob,
    float* __restrict__ Out)
{
    __shared__ u16 KP[8][64][16];    // wave-private K tile (16 KB)
    __shared__ u16 At[16][136];      // attended tokens (4.4 KB)

    const u16* qwb  = Wb;
    const u16* owb  = Wb + 49152;
    const u16* lnwb = Wb + 65536;
    const u16* lnbb = Wb + 65664;
    const u16* kvbb = Wb + 65792;

    // Bijective XCD swizzle: xcd = blk&7 -> one batch-half per XCD.
    int blk = blockIdx.x;
    int xcd = blk & 7, jj = blk >> 3;   // jj 0..71
    int b = xcd >> 1;
    int wr = (xcd & 1) * 6 + jj / 12;
    int wc = jj % 12;

    int t = threadIdx.x;
    int lane = t & 63, wave = t >> 6, n15 = lane & 15, quad = lane >> 4;
    v4f zz4 = {0.f, 0.f, 0.f, 0.f};
    const float QSCALE = 0.25f * 1.44269504f;

    u16* KPw = &KP[wave][0][0];
    const u16* kwave = KVh + (size_t)wave * 46080;
    const u16* vrow0 = VTg + (size_t)b * 92160
                     + (size_t)(wave * 16 + n15) * 720 + quad * 4;

    // --- issue local-K slice immediately (boundary lanes -> clamped addr) ---
    int fh = lane >> 3, fw = lane & 7;
    int hh = wr * 4 - 2 + fh, ww = wc * 4 - 2 + fw;
    bool kvalid = (hh >= 0 && hh < 48 && ww >= 0 && ww < 48);
    int hc = min(max(hh, 0), 47), wcc = min(max(ww, 0), 47);
    v8s kN0, kN1;
    {
        const u16* s = Klh + ((size_t)((wave * 4 + b) * 2304 + hc * 48 + wcc)) * 16;
        kN0 = *(const v8s_am*)s; kN1 = *(const v8s_am*)(s + 8);
    }

    // --- per-lane LN'd window token B-fragments (tok = n15) ---
    int qh = wr * 4 + (n15 >> 2), qw_ = wc * 4 + (n15 & 3);
    int qpix = b * 2304 + qh * 48 + qw_;
    float mu = MuRs[qpix * 2], rstd = MuRs[qpix * 2 + 1];
    v8s xln[4];
#pragma unroll
    for (int kc = 0; kc < 4; ++kc) {
        v8s x  = *(const v8s_am*)&Xt[(size_t)qpix * 128 + kc * 32 + quad * 8];
        v8s lw = *(const v8s_am*)&lnwb[kc * 32 + quad * 8];
        v8s lb = *(const v8s_am*)&lnbb[kc * 32 + quad * 8];
        v8s y;
#pragma unroll
        for (int j = 0; j < 8; ++j)
            y[j] = (short)f2b((b2f((u16)x[j]) - mu) * rstd * b2f((u16)lw[j]) + b2f((u16)lb[j]));
        xln[kc] = y;
    }

    // --- Q projection TRANSPOSED for head=wave: D[d=quad*4+r][q=n15] ---
    v4s qf;
    {
        int n0 = wave * 16;
        v4f qacc = zz4;
#pragma unroll
        for (int kc = 0; kc < 4; ++kc) {
            v8s aw = *(const v8s_am*)&qwb[((size_t)(n0 + n15)) * 128 + kc * 32 + quad * 8];
            qacc = MFMA_BF16(aw, xln[kc], qacc);
        }
#pragma unroll
        for (int r = 0; r < 4; ++r)
            qf[r] = (short)f2b((qacc[r] + qb[n0 + quad * 4 + r]) * QSCALE);
    }

    // --- boundary lanes: local K = bias (reference zero-pads features) ---
    {
        v8s kb0 = *(const v8s_am*)&kvbb[wave * 16];
        v8s kb1 = *(const v8s_am*)&kvbb[wave * 16 + 8];
        if (!kvalid) { kN0 = kb0; kN1 = kb1; }
    }

    v4f oacc = zz4;
    float ls = 0.f;

    // --- stage local K tile; issue pooled tile-0 K ---
    *(v8s_am*)&KPw[lane * 16]     = kN0;
    *(v8s_am*)&KPw[lane * 16 + 8] = kN1;
    {
        const u16* s = kwave + (size_t)(b * 576 + lane) * 16;
        kN0 = *(const v8s_am*)s; kN1 = *(const v8s_am*)(s + 8);
    }

    // --- local chunk: K from KP, V contiguous from padded Vlh ---
    {
        const u16* vbaseL = Vlh + ((size_t)((wave * 16 + n15) * 4 + b)) * 2704
                          + (wr * 4 + (quad >> 1)) * 52 + wc * 4 + (quad & 1) * 4;
#pragma unroll
        for (int g = 0; g < 4; ++g) {
            v4s kf = *(const v4s_am*)&KPw[(g * 16 + n15) * 16 + quad * 4];
            v4s vf = *(const v4s_am*)(vbaseL + g * 104);   // g*2 rows of 52
            v4f St = MFMA16(kf, qf, zz4);       // S^T[tok=quad*4+r][q=n15]
            float p0 = EXP2(St[0]), p1 = EXP2(St[1]);
            float p2 = EXP2(St[2]), p3 = EXP2(St[3]);
            ls += (p0 + p1) + (p2 + p3);
            v4s pk = {(short)f2b(p0), (short)f2b(p1), (short)f2b(p2), (short)f2b(p3)};
            oacc = MFMA16(vf, pk, oacc);        // O^T[ch=quad*4+r][q=n15]
        }
    }

    // --- stage pooled tile 0; issue tile-1 K ---
    *(v8s_am*)&KPw[lane * 16]     = kN0;
    *(v8s_am*)&KPw[lane * 16 + 8] = kN1;
    {
        const u16* s = kwave + (size_t)(b * 576 + 64 + lane) * 16;
        kN0 = *(const v8s_am*)s; kN1 = *(const v8s_am*)(s + 8);
    }

    // --- pooled tiles 0..10: barrier-free, wave-private single buffer ---
    for (int tb = 0; tb <= 10; ++tb) {
        v4s kf[4];
#pragma unroll
        for (int g = 0; g < 4; ++g)
            kf[g] = *(const v4s_am*)&KPw[(g * 16 + n15) * 16 + quad * 4];
        *(v8s_am*)&KPw[lane * 16]     = kN0;
        *(v8s_am*)&KPw[lane * 16 + 8] = kN1;
        if (tb < 10) {   // issue K(tb+2): tiles 2..11
            int t2 = tb + 2;
            int row = (t2 < 9) ? (b * 576 + t2 * 64 + lane)
                               : (2304 + b * 144 + (t2 - 9) * 64 + lane);
            if (t2 == 11) row = 2304 + b * 144 + 128 + n15;  // 16 rows, dup x4
            const u16* s = kwave + (size_t)row * 16;
            kN0 = *(const v8s_am*)s; kN1 = *(const v8s_am*)(s + 8);
        }
        v4s vp[4];
#pragma unroll
        for (int g = 0; g < 4; ++g)
            vp[g] = *(const v4s_am*)(vrow0 + tb * 64 + g * 16);
#pragma unroll
        for (int g = 0; g < 4; ++g) {
            v4f St = MFMA16(kf[g], qf, zz4);
            float p0 = EXP2(St[0]), p1 = EXP2(St[1]);
            float p2 = EXP2(St[2]), p3 = EXP2(St[3]);
            ls += (p0 + p1) + (p2 + p3);
            v4s pk = {(short)f2b(p0), (short)f2b(p1), (short)f2b(p2), (short)f2b(p3)};
            oacc = MFMA16(vp[g], pk, oacc);
        }
    }
    // --- tile 11: 16 toks (glo 128..143), staged at tb==10 ---
    {
        v4s kf = *(const v4s_am*)&KPw[n15 * 16 + quad * 4];
        v4s vf = *(const v4s_am*)(vrow0 + 704);
        v4f St = MFMA16(kf, qf, zz4);
        float p0 = EXP2(St[0]), p1 = EXP2(St[1]);
        float p2 = EXP2(St[2]), p3 = EXP2(St[3]);
        ls += (p0 + p1) + (p2 + p3);
        v4s pk = {(short)f2b(p0), (short)f2b(p1), (short)f2b(p2), (short)f2b(p3)};
        oacc = MFMA16(vf, pk, oacc);
    }

    // --- l reduce (across quads); write attended into At ---
    ls += __shfl_xor(ls, 16);
    ls += __shfl_xor(ls, 32);
    {
        float inv = 1.f / ls;
        v4s a4 = {(short)f2b(oacc[0] * inv), (short)f2b(oacc[1] * inv),
                  (short)f2b(oacc[2] * inv), (short)f2b(oacc[3] * inv)};
        *(v4s_am*)&At[n15][wave * 16 + quad * 4] = a4;
    }
    __syncthreads();    // the only barrier in this kernel

    // --- out projection (16 out-ch per wave) + bias + residual, NCHW ---
    {
        int n0 = wave * 16;
        v4f oa = zz4;
#pragma unroll
        for (int kc = 0; kc < 4; ++kc) {
            v8s af = *(const v8s_am*)&At[n15][kc * 32 + quad * 8];
            v8s bf = *(const v8s_am*)&owb[((size_t)(n0 + n15)) * 128 + kc * 32 + quad * 8];
            oa = MFMA_BF16(af, bf, oa);
        }
        int c = n0 + n15;
        float bv = ob[c];
#pragma unroll
        for (int r = 0; r < 4; ++r) {
            int pix = quad * 4 + r;
            int hh2 = wr * 4 + (pix >> 2), ww2 = wc * 4 + (pix & 3);
            size_t idx = ((size_t)(b * 128 + c)) * 2304 + hh2 * 48 + ww2;
            Out[idx] = oa[r] + bv + F[idx];
        }
    }
}

// ---------------------------------------------------------------------------
extern "C" void kernel_launch(void* const* d_in, const int* in_sizes, int n_in,
                              void* d_out, int out_size, void* d_ws, size_t ws_size,
                              hipStream_t stream)
{
    const float* F   = (const float*)d_in[0];
    const float* lnw = (const float*)d_in[1];
    const float* lnb = (const float*)d_in[2];
    const float* qw  = (const float*)d_in[3];
    const float* qb  = (const float*)d_in[4];
    const float* kvw = (const float*)d_in[5];
    const float* kvb = (const float*)d_in[6];
    const float* ow  = (const float*)d_in[7];
    const float* ob  = (const float*)d_in[8];
    float* Out = (float*)d_out;

    u16* ws    = (u16*)d_ws;
    u16* Xt    = ws;                     // 9216*128     = 1,179,648 u16
    u16* Pml   = Xt + 9216 * 128;        // 2880*128     =   368,640
    u16* KVh   = Pml + 2880 * 128;       // 8*2880*16    =   368,640
    u16* VTg   = KVh + 8 * 2880 * 16;    // 4*128*720    =   368,640
    u16* Klh   = VTg + 4 * 128 * 720;    // 8*4*2304*16  = 1,179,648
    u16* Vlh   = Klh + 8 * 4 * 2304 * 16;// 128*4*2704   = 1,384,448
    u16* Wb    = Vlh + 128 * 4 * 2704;   // 66,048 [qwb|kvwb|owb|lnwb|lnbb|kvbb]
    float* MuRs = (float*)(Wb + 66048);  // 9216*2 fp32
    // total: ~9.9 MiB
    u16* kvwb = Wb + 16384;

    k_prep<<<653, 256, 0, stream>>>(F, qw, kvw, ow, lnw, lnb, kvb,
                                    Xt, Wb, MuRs, Pml, Vlh);
    k_gemm_kv<<<dim3(189, 4), 256, 0, stream>>>(Xt, Pml, kvwb, kvb,
                                                KVh, VTg, Klh, Vlh);
    k_attn_fused<<<576, 512, 0, stream>>>(F, Xt, MuRs, KVh, VTg, Klh, Vlh,
                                          Wb, qb, ob, Out);
}

// Round 13
// 118.344 us; speedup vs baseline: 1.1131x; 1.0279x over previous
//
#include <hip/hip_runtime.h>

// FocalSelfAttention on MI355X. fp32 I/O, bf16 MFMA compute, fp32 accum.
// B=4, C=128, H=W=48, WS=4 -> 144 windows/batch, 16 q/window, NH=8, hd=16,
// Nkv = 64 local + 720 pooled.
//
// v21 = v20 (best: 121.6) + two changes:
//  1. k_gemm_kv epilogue through LDS: acc -> Ct[64][72] (token-major for K
//     dests, channel-major for V dests), then contiguous 16-u16 stores per
//     thread (2x v8s for Klh/KVh/VTg, 8x u32 for pad-shifted Vlh). v20 wrote
//     each element as a 2B scatter (16 store-instr/thread, ~3.1M stores).
//  2. LN hoisted into k_prep: writes Xln[9216][128] bf16 (same math, once
//     per token); attn's prologue becomes 4 v8s loads (was 8x-redundant
//     per-wave LN). MuRs removed.

typedef unsigned short u16;
typedef short v8s __attribute__((ext_vector_type(8)));
typedef v8s __attribute__((may_alias)) v8s_am;
typedef short v4s __attribute__((ext_vector_type(4)));
typedef v4s __attribute__((may_alias)) v4s_am;
typedef float v4f __attribute__((ext_vector_type(4)));

#define MFMA_BF16(a, b, c) __builtin_amdgcn_mfma_f32_16x16x32_bf16(a, b, c, 0, 0, 0)

#if __has_builtin(__builtin_amdgcn_mfma_f32_16x16x16bf16_1k)
#define MFMA16(a, b, c) __builtin_amdgcn_mfma_f32_16x16x16bf16_1k(a, b, c, 0, 0, 0)
#else
static __device__ __forceinline__ v4f mfma16_fb(v4s a, v4s b, v4f c) {
    v8s a8 = {a[0], a[1], a[2], a[3], 0, 0, 0, 0};
    v8s b8 = {b[0], b[1], b[2], b[3], 0, 0, 0, 0};
    return MFMA_BF16(a8, b8, c);
}
#define MFMA16(a, b, c) mfma16_fb(a, b, c)
#endif

#if __has_builtin(__builtin_amdgcn_exp2f)
#define EXP2(x) __builtin_amdgcn_exp2f(x)
#else
#define EXP2(x) exp2f(x)
#endif

__device__ __forceinline__ float b2f(u16 u) {
    union { unsigned int i; float f; } x;
    x.i = ((unsigned int)u) << 16;
    return x.f;
}
__device__ __forceinline__ u16 f2b(float f) {
    union { float f; unsigned int i; } x;
    x.f = f;
    unsigned int u = x.i;
    return (u16)((u + 0x7fffu + ((u >> 16) & 1u)) >> 16);
}

// ---------------------------------------------------------------------------
// Kernel 1: blocks 0..287 transpose F->Xt + LN -> Xln; 288..303 weights
// (blk 288 also ln params + bf16 kv-bias); 304..483 pooled tokens -> Pml;
// 484..652 fill Vlh with V-bias (pad region; reference zero-pads features).
__global__ __launch_bounds__(256) void k_prep(
    const float* __restrict__ F,
    const float* __restrict__ qw, const float* __restrict__ kvw,
    const float* __restrict__ ow,
    const float* __restrict__ lnw, const float* __restrict__ lnb,
    const float* __restrict__ kvb,
    u16* __restrict__ Xt, u16* __restrict__ Xln, u16* __restrict__ Wb,
    u16* __restrict__ Pml, u16* __restrict__ Vlh)
{
    int blk = blockIdx.x;
    int t = threadIdx.x;
    if (blk >= 484) {   // ---- Vlh bias-fill: 169 blocks x 8192 u16 ----
        int base = (blk - 484) * 8192 + t * 32;
#pragma unroll
        for (int k = 0; k < 4; ++k) {
            int off = base + k * 8;
            int ch = off / 10816;            // 4*2704 u16 per channel
            u16 bv = f2b(kvb[128 + ch]);
            v8s o = {(short)bv, (short)bv, (short)bv, (short)bv,
                     (short)bv, (short)bv, (short)bv, (short)bv};
            *(v8s_am*)&Vlh[off] = o;
        }
        return;
    }
    if (blk >= 304) {   // ---- pool part: 180 blocks ----
        int gid = (blk - 304) * 256 + t;
        int row = gid >> 4;
        int seg = gid & 15;
        v8s outv;
        if (row < 2304) {        // mid: avg 2x2
            int b = row / 576, r = row % 576;
            int i = r / 24, j = r % 24;
#pragma unroll
            for (int jc = 0; jc < 8; ++jc) {
                int c = seg * 8 + jc;
                const float* src = F + ((size_t)(b * 128 + c)) * 2304 + (2 * i) * 48 + 2 * j;
                float2 a = *(const float2*)src;
                float2 d = *(const float2*)(src + 48);
                outv[jc] = (short)f2b((a.x + a.y + d.x + d.y) * 0.25f);
            }
        } else {                 // glo: avg 4x4
            int r2 = row - 2304;
            int b = r2 / 144, r = r2 % 144;
            int i = r / 12, j = r % 12;
#pragma unroll
            for (int jc = 0; jc < 8; ++jc) {
                int c = seg * 8 + jc;
                const float* src = F + ((size_t)(b * 128 + c)) * 2304 + (4 * i) * 48 + 4 * j;
                float s = 0.f;
#pragma unroll
                for (int di = 0; di < 4; ++di) {
                    float4 v = *(const float4*)(src + di * 48);
                    s += (v.x + v.y) + (v.z + v.w);
                }
                outv[jc] = (short)f2b(s * 0.0625f);
            }
        }
        *(v8s_am*)&Pml[((size_t)row) * 128 + seg * 8] = outv;
        return;
    }
    if (blk >= 288) {   // ---- weight conversion: 16 blocks ----
        int base = (blk - 288) * 4096 + t * 16;
#pragma unroll
        for (int i = 0; i < 4; ++i) {
            int idx = base + i * 4;
            const float* src; int off;
            if (idx < 16384)      { src = qw;  off = idx; }
            else if (idx < 49152) { src = kvw; off = idx - 16384; }
            else                  { src = ow;  off = idx - 49152; }
            float4 v = *(const float4*)(src + off);
            unsigned long long packed =
                (unsigned long long)f2b(v.x) |
                ((unsigned long long)f2b(v.y) << 16) |
                ((unsigned long long)f2b(v.z) << 32) |
                ((unsigned long long)f2b(v.w) << 48);
            *(unsigned long long*)(Wb + idx) = packed;
        }
        if (blk == 288) {
            Wb[65536 + t] = f2b(t < 128 ? lnw[t] : lnb[t - 128]);
            Wb[65792 + t] = f2b(kvb[t]);     // bf16 kv-bias (K part used)
        }
        return;
    }
    // ---- transpose + LN: 288 blocks ----
    __shared__ u16 X[128][34];
    __shared__ float Lw[128], Lb[128];
    if (t < 128) Lw[t] = lnw[t];
    else         Lb[t - 128] = lnb[t - 128];
    int b = blk / 72;
    int p0 = (blk % 72) * 32;
#pragma unroll 4
    for (int i = 0; i < 16; ++i) {
        int c = i * 8 + (t >> 5);
        int pix = t & 31;
        X[c][pix] = f2b(F[((size_t)(b * 128 + c)) * 2304 + p0 + pix]);
    }
    __syncthreads();
    int pix = t >> 3;
    int c0 = (t & 7) * 16;
    size_t row = (size_t)(b * 2304 + p0 + pix) * 128;
    float s = 0.f, s2 = 0.f;
#pragma unroll
    for (int sg = 0; sg < 2; ++sg) {
        v8s raw;
#pragma unroll
        for (int j = 0; j < 8; ++j) {
            u16 u = X[c0 + sg * 8 + j][pix];
            raw[j] = (short)u;
            float v = b2f(u);
            s += v; s2 += v * v;
        }
        *(v8s_am*)&Xt[row + c0 + sg * 8] = raw;
    }
    // butterfly over the 8 lanes sharing one pixel -> all lanes get sums
    s += __shfl_xor(s, 1);  s2 += __shfl_xor(s2, 1);
    s += __shfl_xor(s, 2);  s2 += __shfl_xor(s2, 2);
    s += __shfl_xor(s, 4);  s2 += __shfl_xor(s2, 4);
    float mean = s * (1.f / 128.f);
    float var = s2 * (1.f / 128.f) - mean * mean;
    float rstd = rsqrtf(var + 1e-5f);
#pragma unroll
    for (int sg = 0; sg < 2; ++sg) {
        v8s o;
#pragma unroll
        for (int j = 0; j < 8; ++j) {
            int c = c0 + sg * 8 + j;
            float v = b2f(X[c][pix]);
            o[j] = (short)f2b((v - mean) * rstd * Lw[c] + Lb[c]);
        }
        *(v8s_am*)&Xln[row + c0 + sg * 8] = o;
    }
}

// ---------------------------------------------------------------------------
// Kernel 2: K/V projection for ALL tokens. Grid (189, 4):
//  gb < 144: local pixel tokens from Xt -> Klh / Vlh (padded 52x52 image)
//  gb >= 144: pooled tokens from Pml -> KVh / VTg
// Epilogue: acc -> LDS Ct[64][72] (K: [tok][ch], V: [ch][tok]) -> contiguous
// 16-u16 per-thread stores (v8s x2; Vlh via u32 x8 due to +2 pad shift).
__global__ __launch_bounds__(256) void k_gemm_kv(
    const u16* __restrict__ Xt,
    const u16* __restrict__ Pml,
    const u16* __restrict__ W,
    const float* __restrict__ bias,
    u16* __restrict__ KVh,
    u16* __restrict__ VTg,
    u16* __restrict__ Klh,
    u16* __restrict__ Vlh)
{
    __shared__ u16 Al[64][136];
    __shared__ u16 Wl[64][136];
    int gb = blockIdx.x;
    bool loc = (gb < 144);
    int tm = loc ? gb * 64 : (gb - 144) * 64;
    int tn = blockIdx.y * 64;
    int t = threadIdx.x;
    {
        int seg = t & 15, r0 = t >> 4;
        const u16* A = loc ? Xt : Pml;
#pragma unroll
        for (int i = 0; i < 4; ++i) {
            int r = r0 + 16 * i;
            *(v8s_am*)&Al[r][seg * 8] = *(const v8s_am*)&A[((size_t)(tm + r)) * 128 + seg * 8];
            *(v8s_am*)&Wl[r][seg * 8] = *(const v8s_am*)&W[((size_t)(tn + r)) * 128 + seg * 8];
        }
    }
    __syncthreads();
    int lane = t & 63, wave = t >> 6;
    int n15 = lane & 15, quad = lane >> 4;
    int wm = (wave & 1) * 32, wn = (wave >> 1) * 32;
    v4f acc[2][2] = {};
#pragma unroll
    for (int kc = 0; kc < 4; ++kc) {
        v8s a[2], bb[2];
#pragma unroll
        for (int im = 0; im < 2; ++im)
            a[im] = *(const v8s_am*)&Al[wm + im * 16 + n15][kc * 32 + quad * 8];
#pragma unroll
        for (int in = 0; in < 2; ++in)
            bb[in] = *(const v8s_am*)&Wl[wn + in * 16 + n15][kc * 32 + quad * 8];
#pragma unroll
        for (int im = 0; im < 2; ++im)
#pragma unroll
            for (int in = 0; in < 2; ++in)
                acc[im][in] = MFMA_BF16(a[im], bb[in], acc[im][in]);
    }
    // --- epilogue through LDS ---
    bool vdst = (tn >= 128);
    __syncthreads();                 // Al/Wl reads complete
    u16* Ct = &Al[0][0];             // [64][72] = 9216 u16 (fits in Al)
#pragma unroll
    for (int in = 0; in < 2; ++in) {
        int nl = wn + in * 16 + n15;
        float bv = bias[tn + nl];
#pragma unroll
        for (int im = 0; im < 2; ++im) {
#pragma unroll
            for (int r = 0; r < 4; ++r) {
                int ml = wm + im * 16 + quad * 4 + r;
                u16 h = f2b(acc[im][in][r] + bv);
                Ct[vdst ? (nl * 72 + ml) : (ml * 72 + nl)] = h;
            }
        }
    }
    __syncthreads();
    {
        int a = t >> 2, sub = t & 3;
        v8s a0 = *(const v8s_am*)&Ct[a * 72 + sub * 16];
        v8s a1 = *(const v8s_am*)&Ct[a * 72 + sub * 16 + 8];
        if (!vdst) {                 // K dests: a = token slot, sub = head slot
            int m = tm + a;
            int headc = (tn >> 4) + sub;
            size_t d; u16* dst;
            if (loc) { int b = m / 2304, px = m % 2304;
                       d = (((size_t)(headc * 4 + b)) * 2304 + px) * 16; dst = Klh; }
            else     { d = ((size_t)headc * 2880 + m) * 16; dst = KVh; }
            *(v8s_am*)&dst[d]     = a0;
            *(v8s_am*)&dst[d + 8] = a1;
        } else {                     // V dests: a = channel slot, sub = 16-tok run
            int ch = (tn - 128) + a;
            int pxo = sub * 16;
            if (loc) {
                int b = tm / 2304;               // uniform (tm mult of 64)
                int s2_ = tm % 2304 + pxo;       // mult of 16 -> run stays in row
                int hh = s2_ / 48, ww = s2_ % 48;
                size_t base = ((size_t)(ch * 4 + b)) * 2704 + (hh + 2) * 52 + ww + 2;
                union { v8s s; unsigned int u[4]; } u0, u1;
                u0.s = a0; u1.s = a1;
#pragma unroll
                for (int k = 0; k < 4; ++k) {
                    *(unsigned int*)&Vlh[base + 2 * k]     = u0.u[k];
                    *(unsigned int*)&Vlh[base + 8 + 2 * k] = u1.u[k];
                }
            } else {
                int m = tm + pxo;                // 16-runs never straddle 2304/576/144
                size_t base;
                if (m < 2304) { int b = m / 576, tok = m % 576;
                                base = ((size_t)(b * 128 + ch)) * 720 + tok; }
                else { int r2 = m - 2304; int b = r2 / 144, tok = 576 + r2 % 144;
                       base = ((size_t)(b * 128 + ch)) * 720 + tok; }
                *(v8s_am*)&VTg[base]     = a0;
                *(v8s_am*)&VTg[base + 8] = a1;
            }
        }
    }
}

// ---------------------------------------------------------------------------
// Kernel 3: fused attention. 576 blocks x 512 thr (8 waves), wave = head.
// LN + local K/V precomputed -> prologue is pure loads. Barrier-free loop
// (wave-private single-buffer KP, per-wave in-order DS). 1 barrier.
__global__ __launch_bounds__(512, 3) void k_attn_fused(
    const float* __restrict__ F,
    const u16* __restrict__ Xln,     // [9216][128] LN'd tokens (bf16)
    const u16* __restrict__ KVh,     // [8][2880][16] pooled K head-major
    const u16* __restrict__ VTg,     // [4][128][720] pooled V^T
    const u16* __restrict__ Klh,     // [8][4][2304][16] local K head-major
    const u16* __restrict__ Vlh,     // [128][4][2704] local V^T padded 52x52
    const u16* __restrict__ Wb,      // [qwb|kvwb|owb|lnwb|lnbb|kvbb]
    const float* __restrict__ qb,
    const float* __restrict__ ob,
    float* __restrict__ Out)
{
    __shared__ u16 KP[8][64][16];    // wave-private K tile (16 KB)
    __shared__ u16 At[16][136];      // attended tokens (4.4 KB)

    const u16* qwb  = Wb;
    const u16* owb  = Wb + 49152;
    const u16* kvbb = Wb + 65792;

    // Bijective XCD swizzle: xcd = blk&7 -> one batch-half per XCD.
    int blk = blockIdx.x;
    int xcd = blk & 7, jj = blk >> 3;   // jj 0..71
    int b = xcd >> 1;
    int wr = (xcd & 1) * 6 + jj / 12;
    int wc = jj % 12;

    int t = threadIdx.x;
    int lane = t & 63, wave = t >> 6, n15 = lane & 15, quad = lane >> 4;
    v4f zz4 = {0.f, 0.f, 0.f, 0.f};
    const float QSCALE = 0.25f * 1.44269504f;

    u16* KPw = &KP[wave][0][0];
    const u16* kwave = KVh + (size_t)wave * 46080;
    const u16* vrow0 = VTg + (size_t)b * 92160
                     + (size_t)(wave * 16 + n15) * 720 + quad * 4;

    // --- issue local-K slice immediately (boundary lanes -> clamped addr) ---
    int fh = lane >> 3, fw = lane & 7;
    int hh = wr * 4 - 2 + fh, ww = wc * 4 - 2 + fw;
    bool kvalid = (hh >= 0 && hh < 48 && ww >= 0 && ww < 48);
    int hc = min(max(hh, 0), 47), wcc = min(max(ww, 0), 47);
    v8s kN0, kN1;
    {
        const u16* s = Klh + ((size_t)((wave * 4 + b) * 2304 + hc * 48 + wcc)) * 16;
        kN0 = *(const v8s_am*)s; kN1 = *(const v8s_am*)(s + 8);
    }

    // --- LN'd window token B-fragments: straight loads from Xln ---
    int qh = wr * 4 + (n15 >> 2), qw_ = wc * 4 + (n15 & 3);
    int qpix = b * 2304 + qh * 48 + qw_;
    v8s xln[4];
#pragma unroll
    for (int kc = 0; kc < 4; ++kc)
        xln[kc] = *(const v8s_am*)&Xln[(size_t)qpix * 128 + kc * 32 + quad * 8];

    // --- Q projection TRANSPOSED for head=wave: D[d=quad*4+r][q=n15] ---
    v4s qf;
    {
        int n0 = wave * 16;
        v4f qacc = zz4;
#pragma unroll
        for (int kc = 0; kc < 4; ++kc) {
            v8s aw = *(const v8s_am*)&qwb[((size_t)(n0 + n15)) * 128 + kc * 32 + quad * 8];
            qacc = MFMA_BF16(aw, xln[kc], qacc);
        }
#pragma unroll
        for (int r = 0; r < 4; ++r)
            qf[r] = (short)f2b((qacc[r] + qb[n0 + quad * 4 + r]) * QSCALE);
    }

    // --- boundary lanes: local K = bias (reference zero-pads features) ---
    {
        v8s kb0 = *(const v8s_am*)&kvbb[wave * 16];
        v8s kb1 = *(const v8s_am*)&kvbb[wave * 16 + 8];
        if (!kvalid) { kN0 = kb0; kN1 = kb1; }
    }

    v4f oacc = zz4;
    float ls = 0.f;

    // --- stage local K tile; issue pooled tile-0 K ---
    *(v8s_am*)&KPw[lane * 16]     = kN0;
    *(v8s_am*)&KPw[lane * 16 + 8] = kN1;
    {
        const u16* s = kwave + (size_t)(b * 576 + lane) * 16;
        kN0 = *(const v8s_am*)s; kN1 = *(const v8s_am*)(s + 8);
    }

    // --- local chunk: K from KP, V contiguous from padded Vlh ---
    {
        const u16* vbaseL = Vlh + ((size_t)((wave * 16 + n15) * 4 + b)) * 2704
                          + (wr * 4 + (quad >> 1)) * 52 + wc * 4 + (quad & 1) * 4;
#pragma unroll
        for (int g = 0; g < 4; ++g) {
            v4s kf = *(const v4s_am*)&KPw[(g * 16 + n15) * 16 + quad * 4];
            v4s vf = *(const v4s_am*)(vbaseL + g * 104);   // g*2 rows of 52
            v4f St = MFMA16(kf, qf, zz4);       // S^T[tok=quad*4+r][q=n15]
            float p0 = EXP2(St[0]), p1 = EXP2(St[1]);
            float p2 = EXP2(St[2]), p3 = EXP2(St[3]);
            ls += (p0 + p1) + (p2 + p3);
            v4s pk = {(short)f2b(p0), (short)f2b(p1), (short)f2b(p2), (short)f2b(p3)};
            oacc = MFMA16(vf, pk, oacc);        // O^T[ch=quad*4+r][q=n15]
        }
    }

    // --- stage pooled tile 0; issue tile-1 K ---
    *(v8s_am*)&KPw[lane * 16]     = kN0;
    *(v8s_am*)&KPw[lane * 16 + 8] = kN1;
    {
        const u16* s = kwave + (size_t)(b * 576 + 64 + lane) * 16;
        kN0 = *(const v8s_am*)s; kN1 = *(const v8s_am*)(s + 8);
    }

    // --- pooled tiles 0..10: barrier-free, wave-private single buffer ---
    for (int tb = 0; tb <= 10; ++tb) {
        v4s kf[4];
#pragma unroll
        for (int g = 0; g < 4; ++g)
            kf[g] = *(const v4s_am*)&KPw[(g * 16 + n15) * 16 + quad * 4];
        *(v8s_am*)&KPw[lane * 16]     = kN0;
        *(v8s_am*)&KPw[lane * 16 + 8] = kN1;
        if (tb < 10) {   // issue K(tb+2): tiles 2..11
            int t2 = tb + 2;
            int row = (t2 < 9) ? (b * 576 + t2 * 64 + lane)
                               : (2304 + b * 144 + (t2 - 9) * 64 + lane);
            if (t2 == 11) row = 2304 + b * 144 + 128 + n15;  // 16 rows, dup x4
            const u16* s = kwave + (size_t)row * 16;
            kN0 = *(const v8s_am*)s; kN1 = *(const v8s_am*)(s + 8);
        }
        v4s vp[4];
#pragma unroll
        for (int g = 0; g < 4; ++g)
            vp[g] = *(const v4s_am*)(vrow0 + tb * 64 + g * 16);
#pragma unroll
        for (int g = 0; g < 4; ++g) {
            v4f St = MFMA16(kf[g], qf, zz4);
            float p0 = EXP2(St[0]), p1 = EXP2(St[1]);
            float p2 = EXP2(St[2]), p3 = EXP2(St[3]);
            ls += (p0 + p1) + (p2 + p3);
            v4s pk = {(short)f2b(p0), (short)f2b(p1), (short)f2b(p2), (short)f2b(p3)};
            oacc = MFMA16(vp[g], pk, oacc);
        }
    }
    // --- tile 11: 16 toks (glo 128..143), staged at tb==10 ---
    {
        v4s kf = *(const v4s_am*)&KPw[n15 * 16 + quad * 4];
        v4s vf = *(const v4s_am*)(vrow0 + 704);
        v4f St = MFMA16(kf, qf, zz4);
        float p0 = EXP2(St[0]), p1 = EXP2(St[1]);
        float p2 = EXP2(St[2]), p3 = EXP2(St[3]);
        ls += (p0 + p1) + (p2 + p3);
        v4s pk = {(short)f2b(p0), (short)f2b(p1), (short)f2b(p2), (short)f2b(p3)};
        oacc = MFMA16(vf, pk, oacc);
    }

    // --- l reduce (across quads); write attended into At ---
    ls += __shfl_xor(ls, 16);
    ls += __shfl_xor(ls, 32);
    {
        float inv = 1.f / ls;
        v4s a4 = {(short)f2b(oacc[0] * inv), (short)f2b(oacc[1] * inv),
                  (short)f2b(oacc[2] * inv), (short)f2b(oacc[3] * inv)};
        *(v4s_am*)&At[n15][wave * 16 + quad * 4] = a4;
    }
    __syncthreads();    // the only barrier in this kernel

    // --- out projection (16 out-ch per wave) + bias + residual, NCHW ---
    {
        int n0 = wave * 16;
        v4f oa = zz4;
#pragma unroll
        for (int kc = 0; kc < 4; ++kc) {
            v8s af = *(const v8s_am*)&At[n15][kc * 32 + quad * 8];
            v8s bf = *(const v8s_am*)&owb[((size_t)(n0 + n15)) * 128 + kc * 32 + quad * 8];
            oa = MFMA_BF16(af, bf, oa);
        }
        int c = n0 + n15;
        float bv = ob[c];
#pragma unroll
        for (int r = 0; r < 4; ++r) {
            int pix = quad * 4 + r;
            int hh2 = wr * 4 + (pix >> 2), ww2 = wc * 4 + (pix & 3);
            size_t idx = ((size_t)(b * 128 + c)) * 2304 + hh2 * 48 + ww2;
            Out[idx] = oa[r] + bv + F[idx];
        }
    }
}

// ---------------------------------------------------------------------------
extern "C" void kernel_launch(void* const* d_in, const int* in_sizes, int n_in,
                              void* d_out, int out_size, void* d_ws, size_t ws_size,
                              hipStream_t stream)
{
    const float* F   = (const float*)d_in[0];
    const float* lnw = (const float*)d_in[1];
    const float* lnb = (const float*)d_in[2];
    const float* qw  = (const float*)d_in[3];
    const float* qb  = (const float*)d_in[4];
    const float* kvw = (const float*)d_in[5];
    const float* kvb = (const float*)d_in[6];
    const float* ow  = (const float*)d_in[7];
    const float* ob  = (const float*)d_in[8];
    float* Out = (float*)d_out;

    u16* ws    = (u16*)d_ws;
    u16* Xt    = ws;                     // 9216*128     = 1,179,648 u16
    u16* Xln   = Xt + 9216 * 128;        // 9216*128     = 1,179,648
    u16* Pml   = Xln + 9216 * 128;       // 2880*128     =   368,640
    u16* KVh   = Pml + 2880 * 128;       // 8*2880*16    =   368,640
    u16* VTg   = KVh + 8 * 2880 * 16;    // 4*128*720    =   368,640
    u16* Klh   = VTg + 4 * 128 * 720;    // 8*4*2304*16  = 1,179,648
    u16* Vlh   = Klh + 8 * 4 * 2304 * 16;// 128*4*2704   = 1,384,448
    u16* Wb    = Vlh + 128 * 4 * 2704;   // 66,048 [qwb|kvwb|owb|lnwb|lnbb|kvbb]
    // total: ~12.1 MiB
    u16* kvwb = Wb + 16384;

    k_prep<<<653, 256, 0, stream>>>(F, qw, kvw, ow, lnw, lnb, kvb,
                                    Xt, Xln, Wb, Pml, Vlh);
    k_gemm_kv<<<dim3(189, 4), 256, 0, stream>>>(Xt, Pml, kvwb, kvb,
                                                KVh, VTg, Klh, Vlh);
    k_attn_fused<<<576, 512, 0, stream>>>(F, Xln, KVh, VTg, Klh, Vlh,
                                          Wb, qb, ob, Out);
}